// Round 1
// 650.283 us; speedup vs baseline: 1.0315x; 1.0315x over previous
//
#include <hip/hip_runtime.h>
#include <hip/hip_bf16.h>

// Problem dims (fixed by reference)
#define L_DIM 2048
#define B_DIM 16
#define NIN   1024
#define NOUT  1024
#define M_DIM (L_DIM * B_DIM)   // 32768 GEMM rows (l*B+b)
#define N_DIM (2 * NOUT)        // 2048 GEMM cols (interleaved gates)
#define K_DIM NIN               // 1024
#define NCOL  (B_DIM * NOUT)    // 16384 independent scan columns
#define NCH   64                // scan chunks over L
#define LC    (L_DIM / NCH)     // 32 steps per chunk

typedef __bf16 bf16x8 __attribute__((ext_vector_type(8)));
typedef float  f32x4  __attribute__((ext_vector_type(4)));
typedef unsigned short us4 __attribute__((ext_vector_type(4)));

// fp32 -> bf16 round-to-nearest-even (inputs are finite; no NaN path needed)
__device__ __forceinline__ unsigned short f2bf(float f) {
    unsigned int u = __float_as_uint(f);
    unsigned int r = (u + 0x7fffu + ((u >> 16) & 1u)) >> 16;
    return (unsigned short)r;
}

// async global->LDS, 16B per lane; LDS dest is wave-uniform base + lane*16
__device__ __forceinline__ void gld_lds16(const void* g, void* l) {
    __builtin_amdgcn_global_load_lds(
        (const __attribute__((address_space(1))) unsigned int*)g,
        (__attribute__((address_space(3))) unsigned int*)l,
        16, 0, 0);
}

// ---------------- input fp32 -> bf16, elementwise (coalesced float4) --------
__global__ void cvt_input_kernel(const float* __restrict__ in,
                                 unsigned short* __restrict__ out) {
    size_t i = ((size_t)blockIdx.x * 256 + threadIdx.x) * 4;
    float4 v = *(const float4*)(in + i);
    us4 o = { f2bf(v.x), f2bf(v.y), f2bf(v.z), f2bf(v.w) };
    *(us4*)(out + i) = o;
}

// ------------- weight fp32 [K][N] -> bf16 transposed [N][K] (LDS tile) ------
__global__ void cvt_weight_kernel(const float* __restrict__ W,
                                  unsigned short* __restrict__ Wt) {
    __shared__ float t[32][33];
    int tx = threadIdx.x, ty = threadIdx.y;           // 32 x 8
    int i0 = blockIdx.y * 32, n0 = blockIdx.x * 32;
    #pragma unroll
    for (int r = 0; r < 4; ++r)
        t[ty + r * 8][tx] = W[(size_t)(i0 + ty + r * 8) * N_DIM + n0 + tx];
    __syncthreads();
    #pragma unroll
    for (int r = 0; r < 4; ++r)
        Wt[(size_t)(n0 + ty + r * 8) * K_DIM + i0 + tx] = f2bf(t[tx][ty + r * 8]);
}

// ---------------- bf16 MFMA GEMM + fused gate epilogue ----------------------
// m97 structure: linear LDS [128][32] (64B rows), global_load_lds width=16,
// quarter-XOR swizzle applied to BOTH the global staging source and the
// ds_read_b128 address (rule #21): phys quarter p of row r holds logical
// quarter p ^ ((r>>1)&3) -> every fragment read is 2-way per bank (free).
#define BM 128
#define BN 128
#define BK 32
#define GRID_WG ((M_DIM / BM) * (N_DIM / BN))   // 4096, divisible by 8

__global__ void gemm_lds_kernel(const unsigned short* __restrict__ Abf,
                                const unsigned short* __restrict__ Wt,
                                const float* __restrict__ bias,
                                float* __restrict__ u0buf,
                                float* __restrict__ fbuf) {
    __shared__ unsigned short As[BM * BK];   // 8 KB, linear, pitch 32 ushorts
    __shared__ unsigned short Bs[BN * BK];   // 8 KB
    __shared__ float sFB[64];

    const int tid = threadIdx.x;

    // bijective XCD swizzle: each XCD gets 512 consecutive logical blocks
    // (32 full by-rows) -> full Wt (4MB bf16) stays L2-resident per XCD.
    int id = blockIdx.x;
    int sw = (id & 7) * (GRID_WG / 8) + (id >> 3);
    const int bm = (sw >> 4) * BM;           // 256 M-blocks
    const int bn = (sw & 15) * BN;           // 16 N-blocks
    const int obase = bn >> 1;

    if (tid < 64) sFB[tid] = bias[NOUT + obase + tid];

    const int lane = tid & 63;
    const int wave = tid >> 6;
    const int wr = wave >> 1;          // 2x2 wave grid, 64x64 per wave
    const int wc = wave & 1;
    const int mrow = lane & 15;        // A row / B col within 16-tile
    const int q    = lane >> 4;        // logical 16B quarter along K (BK=32)

    // ---- staging geometry: per wave 2 chunks of 16 rows (1KB each) ----
    // lane l covers phys LDS bytes chunk*1024 + l*16
    //   -> row = chunk*16 + (l>>2), phys quarter = l&3
    //   -> logical (global) quarter = (l&3) ^ ((l>>3)&3)   [= p ^ ((row>>1)&3)]
    const int srow = lane >> 2;
    const int logq = (lane & 3) ^ ((lane >> 3) & 3);
    const int c0 = wave * 2, c1 = c0 + 1;
    const unsigned short* aS0 = Abf + (size_t)(bm + c0 * 16 + srow) * K_DIM + logq * 8;
    const unsigned short* aS1 = Abf + (size_t)(bm + c1 * 16 + srow) * K_DIM + logq * 8;
    const unsigned short* bS0 = Wt  + (size_t)(bn + c0 * 16 + srow) * K_DIM + logq * 8;
    const unsigned short* bS1 = Wt  + (size_t)(bn + c1 * 16 + srow) * K_DIM + logq * 8;
    unsigned short* aL0 = &As[c0 * 512];
    unsigned short* aL1 = &As[c1 * 512];
    unsigned short* bL0 = &Bs[c0 * 512];
    unsigned short* bL1 = &Bs[c1 * 512];

    f32x4 acc[4][4];
    #pragma unroll
    for (int i = 0; i < 4; ++i)
        #pragma unroll
        for (int j = 0; j < 4; ++j)
            acc[i][j] = (f32x4){0.f, 0.f, 0.f, 0.f};

    const int pq = q ^ ((mrow >> 1) & 3);   // read-side swizzled quarter

    for (int k0 = 0; k0 < K_DIM; k0 += BK) {
        gld_lds16(aS0 + k0, aL0);
        gld_lds16(aS1 + k0, aL1);
        gld_lds16(bS0 + k0, bL0);
        gld_lds16(bS1 + k0, bL1);
        __syncthreads();   // drains vmcnt(0): tiles resident

        bf16x8 a[4], b[4];
        #pragma unroll
        for (int mt = 0; mt < 4; ++mt)
            a[mt] = *(const bf16x8*)&As[(wr * 64 + mt * 16 + mrow) * BK + pq * 8];
        #pragma unroll
        for (int nt = 0; nt < 4; ++nt)
            b[nt] = *(const bf16x8*)&Bs[(wc * 64 + nt * 16 + mrow) * BK + pq * 8];
        #pragma unroll
        for (int mt = 0; mt < 4; ++mt)
            #pragma unroll
            for (int nt = 0; nt < 4; ++nt)
                acc[mt][nt] = __builtin_amdgcn_mfma_f32_16x16x32_bf16(
                    a[mt], b[nt], acc[mt][nt], 0, 0, 0);
        __syncthreads();   // all waves done reading before next-tile DMA
    }

    // ---- epilogue: pair even/odd columns via shfl_xor(1); lane parity == col parity
    const bool isOdd = (mrow & 1);
    #pragma unroll
    for (int mt = 0; mt < 4; ++mt) {
        #pragma unroll
        for (int nt = 0; nt < 4; ++nt) {
            int gcol = bn + wc * 64 + nt * 16 + mrow;
            int o = gcol >> 1;
            float fb = sFB[o - obase];
            #pragma unroll
            for (int r = 0; r < 4; ++r) {
                float x = acc[mt][nt][r];
                float p = __shfl_xor(x, 1, 64);            // partner column's value
                float uo = isOdd ? x : p;                  // the odd-gate pre-act
                float f = 1.f / (1.f + __expf(-(uo + fb)));
                int grow = bm + wr * 64 + mt * 16 + (lane >> 4) * 4 + r;
                size_t oi = (size_t)grow * NOUT + o;
                if (isOdd) fbuf[oi]  = f;
                else       u0buf[oi] = x * (1.f - f);
            }
        }
    }
}

// ---- fallback GEMM (fp32 A staged+converted in-kernel; only if ws too small)
#define LDAS 40
__global__ void gemm_f32_kernel(const float* __restrict__ A32,
                                const unsigned short* __restrict__ Wt,
                                const float* __restrict__ bias,
                                float* __restrict__ u0buf,
                                float* __restrict__ fbuf) {
    __shared__ unsigned short As[BM * LDAS];
    __shared__ unsigned short Bs[BN * LDAS];
    __shared__ float sFB[64];

    const int tid = threadIdx.x;
    const int bm = blockIdx.y * BM;
    const int bn = blockIdx.x * BN;
    const int obase = bn >> 1;

    if (tid < 64) sFB[tid] = bias[NOUT + obase + tid];

    const int lane = tid & 63;
    const int wave = tid >> 6;
    const int wr = wave >> 1;
    const int wc = wave & 1;
    const int mrow = lane & 15;
    const int kq = (lane >> 4) * 8;

    f32x4 acc[4][4];
    #pragma unroll
    for (int i = 0; i < 4; ++i)
        #pragma unroll
        for (int j = 0; j < 4; ++j)
            acc[i][j] = (f32x4){0.f, 0.f, 0.f, 0.f};

    for (int k0 = 0; k0 < K_DIM; k0 += BK) {
        #pragma unroll
        for (int r = 0; r < 4; ++r) {
            int idx = tid + r * 256;
            int row = idx >> 3;
            int kc  = (idx & 7) << 2;
            float4 v = *(const float4*)&A32[(size_t)(bm + row) * K_DIM + k0 + kc];
            us4 o = { f2bf(v.x), f2bf(v.y), f2bf(v.z), f2bf(v.w) };
            *(us4*)&As[row * LDAS + kc] = o;
        }
        #pragma unroll
        for (int r = 0; r < 2; ++r) {
            int idx = tid + r * 256;
            int row = idx >> 2;
            int kc  = (idx & 3) << 3;
            *(uint4*)&Bs[row * LDAS + kc] =
                *(const uint4*)&Wt[(size_t)(bn + row) * K_DIM + k0 + kc];
        }
        __syncthreads();

        bf16x8 a[4], b[4];
        #pragma unroll
        for (int mt = 0; mt < 4; ++mt)
            a[mt] = *(const bf16x8*)&As[(wr * 64 + mt * 16 + mrow) * LDAS + kq];
        #pragma unroll
        for (int nt = 0; nt < 4; ++nt)
            b[nt] = *(const bf16x8*)&Bs[(wc * 64 + nt * 16 + mrow) * LDAS + kq];
        #pragma unroll
        for (int mt = 0; mt < 4; ++mt)
            #pragma unroll
            for (int nt = 0; nt < 4; ++nt)
                acc[mt][nt] = __builtin_amdgcn_mfma_f32_16x16x32_bf16(
                    a[mt], b[nt], acc[mt][nt], 0, 0, 0);
        __syncthreads();
    }

    const bool isOdd = (mrow & 1);
    #pragma unroll
    for (int mt = 0; mt < 4; ++mt) {
        #pragma unroll
        for (int nt = 0; nt < 4; ++nt) {
            int gcol = bn + wc * 64 + nt * 16 + mrow;
            int o = gcol >> 1;
            float fb = sFB[o - obase];
            #pragma unroll
            for (int r = 0; r < 4; ++r) {
                float x = acc[mt][nt][r];
                float p = __shfl_xor(x, 1, 64);
                float uo = isOdd ? x : p;
                float f = 1.f / (1.f + __expf(-(uo + fb)));
                int grow = bm + wr * 64 + mt * 16 + (lane >> 4) * 4 + r;
                size_t oi = (size_t)grow * NOUT + o;
                if (isOdd) fbuf[oi]  = f;
                else       u0buf[oi] = x * (1.f - f);
            }
        }
    }
}

// ================= chunked scan (3 phases), float4-vectorized ===============
// Phase 1: per (4 cols, chunk c): compose chunk transform (F, U) with c_in = 0.
__global__ void scan_p1_kernel(const float* __restrict__ fgate,
                               const float* __restrict__ u0,     // cs buffer
                               float* __restrict__ Fbuf,
                               float* __restrict__ Ubuf) {
    int j4 = blockIdx.x * 256 + threadIdx.x;    // 0..NCOL/4-1
    int ch = blockIdx.y;                        // chunk 0..NCH-1
    size_t base = (size_t)ch * LC * NCOL + (size_t)j4 * 4;
    f32x4 F = {1.f, 1.f, 1.f, 1.f};
    f32x4 U = {0.f, 0.f, 0.f, 0.f};
    #pragma unroll 8
    for (int l = 0; l < LC; ++l) {
        size_t idx = base + (size_t)l * NCOL;
        f32x4 ft = *(const f32x4*)(fgate + idx);
        f32x4 ut = *(const f32x4*)(u0 + idx);
        #pragma unroll
        for (int c = 0; c < 4; ++c) {
            U[c] = fmaf(U[c], ft[c], ut[c]);
            F[c] = F[c] * ft[c];
        }
    }
    size_t ci = (size_t)ch * NCOL + (size_t)j4 * 4;
    *(f32x4*)(Fbuf + ci) = F;
    *(f32x4*)(Ubuf + ci) = U;
}

// Phase 2: per col, sequentially combine NCH chunk transforms -> carry-ins.
__global__ void scan_p2_kernel(const float* __restrict__ Fbuf,
                               const float* __restrict__ Ubuf,
                               const float* __restrict__ c_init,
                               float* __restrict__ carry,
                               float* __restrict__ c_final) {
    int j = blockIdx.x * 256 + threadIdx.x;
    float c = c_init[j];
    #pragma unroll
    for (int ch = 0; ch < NCH; ++ch) {
        size_t ci = (size_t)ch * NCOL + j;
        carry[ci] = c;
        c = fmaf(Fbuf[ci], c, Ubuf[ci]);
    }
    c_final[j] = c;
}

// Phase 3: per (4 cols, chunk): replay the exact FMA chain from carry-in.
__global__ void scan_p3_kernel(const float* __restrict__ fgate,
                               const float* __restrict__ carry,
                               float* __restrict__ cs) {          // holds u0
    int j4 = blockIdx.x * 256 + threadIdx.x;
    int ch = blockIdx.y;
    size_t base = (size_t)ch * LC * NCOL + (size_t)j4 * 4;
    f32x4 c = *(const f32x4*)(carry + (size_t)ch * NCOL + (size_t)j4 * 4);
    #pragma unroll 8
    for (int l = 0; l < LC; ++l) {
        size_t idx = base + (size_t)l * NCOL;
        f32x4 ft = *(const f32x4*)(fgate + idx);
        f32x4 ut = *(const f32x4*)(cs + idx);
        #pragma unroll
        for (int cc = 0; cc < 4; ++cc)
            c[cc] = fmaf(c[cc], ft[cc], ut[cc]);
        *(f32x4*)(cs + idx) = c;
    }
}

// Fallback single-pass scan (only if ws too small for chunk buffers)
__global__ void scan_kernel(const float* __restrict__ fgate,
                            const float* __restrict__ c_init,
                            float* __restrict__ cs,
                            float* __restrict__ c_final) {
    int j = blockIdx.x * 256 + threadIdx.x;
    float c = c_init[j];
    #pragma unroll 4
    for (int l = 0; l < L_DIM; ++l) {
        size_t idx = (size_t)l * NCOL + j;
        float ft = fgate[idx];
        float u  = cs[idx];
        c = fmaf(c, ft, u);
        cs[idx] = c;
    }
    c_final[j] = c;
}

extern "C" void kernel_launch(void* const* d_in, const int* in_sizes, int n_in,
                              void* d_out, int out_size, void* d_ws, size_t ws_size,
                              hipStream_t stream) {
    const float* input  = (const float*)d_in[0];  // [L,B,NIN]
    const float* c_init = (const float*)d_in[1];  // [B,NOUT]
    const float* weight = (const float*)d_in[2];  // [NIN, 2*NOUT]
    const float* bias   = (const float*)d_in[3];  // [2*NOUT]

    float* out_cs = (float*)d_out;                         // [L,B,NOUT]
    float* out_cf = out_cs + (size_t)L_DIM * B_DIM * NOUT; // [B,NOUT]
    float* out_fg = out_cf + (size_t)B_DIM * NOUT;         // [L,B,NOUT]

    // ws layout: [Wt bf16 4MB][Abf bf16 64MB][F 4MB][U 4MB][carry 4MB]
    size_t wt_bytes = (size_t)N_DIM * K_DIM * sizeof(unsigned short);
    size_t wt_pad   = (wt_bytes + 255) & ~(size_t)255;
    size_t a_bytes  = (size_t)M_DIM * K_DIM * sizeof(unsigned short);
    size_t ch_bytes = (size_t)NCH * NCOL * sizeof(float);  // 4 MB each
    unsigned short* Wt  = (unsigned short*)d_ws;
    unsigned short* Abf = (unsigned short*)((char*)d_ws + wt_pad);
    bool pre_a = (ws_size >= wt_pad + a_bytes);
    size_t scan_off = pre_a ? (wt_pad + a_bytes) : wt_pad;
    float* Fbuf  = (float*)((char*)d_ws + scan_off);
    float* Ubuf  = Fbuf + NCH * NCOL;
    float* carry = Ubuf + NCH * NCOL;
    bool chunked = (ws_size >= scan_off + 3 * ch_bytes);

    // 1) weight fp32 [K][N] -> bf16 Wt [N][K]
    cvt_weight_kernel<<<dim3(N_DIM / 32, K_DIM / 32), dim3(32, 8), 0, stream>>>(weight, Wt);

    // 2) input fp32 -> bf16 (skippable fallback if ws too small)
    if (pre_a) {
        int nblk = (M_DIM * K_DIM) / (4 * 256);  // 32768
        cvt_input_kernel<<<nblk, 256, 0, stream>>>(input, Abf);
    }

    // 3) GEMM + gate epilogue: u0 -> out_cs (temp), forget -> out_fg
    if (pre_a) {
        gemm_lds_kernel<<<GRID_WG, 256, 0, stream>>>(Abf, Wt, bias, out_cs, out_fg);
    } else {
        dim3 ggrid(N_DIM / BN, M_DIM / BM);      // (16, 256)
        gemm_f32_kernel<<<ggrid, 256, 0, stream>>>(input, Wt, bias, out_cs, out_fg);
    }

    // 4) recurrence: chunked 3-phase scan (falls back to single-pass if no ws)
    if (chunked) {
        dim3 sgrid(NCOL / 1024, NCH);            // (16, 64), float4 per thread
        scan_p1_kernel<<<sgrid, 256, 0, stream>>>(out_fg, out_cs, Fbuf, Ubuf);
        scan_p2_kernel<<<NCOL / 256, 256, 0, stream>>>(Fbuf, Ubuf, c_init, carry, out_cf);
        scan_p3_kernel<<<sgrid, 256, 0, stream>>>(out_fg, carry, out_cs);
    } else {
        scan_kernel<<<NCOL / 256, 256, 0, stream>>>(out_fg, c_init, out_cs, out_cf);
    }
}

// Round 2
// 645.796 us; speedup vs baseline: 1.0387x; 1.0069x over previous
//
#include <hip/hip_runtime.h>
#include <hip/hip_bf16.h>

// Problem dims (fixed by reference)
#define L_DIM 2048
#define B_DIM 16
#define NIN   1024
#define NOUT  1024
#define M_DIM (L_DIM * B_DIM)   // 32768 GEMM rows (l*B+b)
#define N_DIM (2 * NOUT)        // 2048 GEMM cols (interleaved gates)
#define K_DIM NIN               // 1024
#define NCOL  (B_DIM * NOUT)    // 16384 independent scan columns
#define NCH   64                // scan chunks over L
#define LC    (L_DIM / NCH)     // 32 steps per chunk

typedef __bf16 bf16x8 __attribute__((ext_vector_type(8)));
typedef float  f32x4  __attribute__((ext_vector_type(4)));
typedef unsigned short us4 __attribute__((ext_vector_type(4)));
typedef unsigned short us8 __attribute__((ext_vector_type(8)));

// fp32 -> bf16 round-to-nearest-even (inputs are finite; no NaN path needed)
__device__ __forceinline__ unsigned short f2bf(float f) {
    unsigned int u = __float_as_uint(f);
    unsigned int r = (u + 0x7fffu + ((u >> 16) & 1u)) >> 16;
    return (unsigned short)r;
}

// async global->LDS, 16B per lane; LDS dest is wave-uniform base + lane*16
__device__ __forceinline__ void gld_lds16(const void* g, void* l) {
    __builtin_amdgcn_global_load_lds(
        (const __attribute__((address_space(1))) unsigned int*)g,
        (__attribute__((address_space(3))) unsigned int*)l,
        16, 0, 0);
}

// ---------------- input fp32 -> bf16, elementwise (coalesced) ---------------
__global__ void cvt_input_kernel(const float* __restrict__ in,
                                 unsigned short* __restrict__ out) {
    size_t i = ((size_t)blockIdx.x * 256 + threadIdx.x) * 8;
    float4 v0 = *(const float4*)(in + i);
    float4 v1 = *(const float4*)(in + i + 4);
    us8 o = { f2bf(v0.x), f2bf(v0.y), f2bf(v0.z), f2bf(v0.w),
              f2bf(v1.x), f2bf(v1.y), f2bf(v1.z), f2bf(v1.w) };
    *(us8*)(out + i) = o;
}

// ------------- weight fp32 [K][N] -> bf16 transposed [N][K] (LDS tile) ------
__global__ void cvt_weight_kernel(const float* __restrict__ W,
                                  unsigned short* __restrict__ Wt) {
    __shared__ float t[32][33];
    int tx = threadIdx.x, ty = threadIdx.y;           // 32 x 8
    int i0 = blockIdx.y * 32, n0 = blockIdx.x * 32;
    #pragma unroll
    for (int r = 0; r < 4; ++r)
        t[ty + r * 8][tx] = W[(size_t)(i0 + ty + r * 8) * N_DIM + n0 + tx];
    __syncthreads();
    #pragma unroll
    for (int r = 0; r < 4; ++r)
        Wt[(size_t)(n0 + ty + r * 8) * K_DIM + i0 + tx] = f2bf(t[tx][ty + r * 8]);
}

// ---------------- bf16 MFMA GEMM + fused gate epilogue ----------------------
// BK=64 structure: linear LDS [128][64] (128B rows), global_load_lds width=16,
// 8-quarter XOR swizzle on BOTH the global staging source and the ds_read
// address (rule #21): phys 16B-quarter p of row r holds logical quarter
// p ^ (r&7). Each fragment ds_read_b128 is then conflict-free; each 8-lane
// staging group covers one contiguous 128B row (coalesced).
// Half the K-steps of BK=32 -> half the vmcnt(0)+barrier drains.
#define BM 128
#define BN 128
#define BK 64
#define GRID_WG ((M_DIM / BM) * (N_DIM / BN))   // 4096, divisible by 8

__global__ void gemm_lds_kernel(const unsigned short* __restrict__ Abf,
                                const unsigned short* __restrict__ Wt,
                                const float* __restrict__ bias,
                                float* __restrict__ u0buf,
                                float* __restrict__ fbuf) {
    __shared__ unsigned short As[BM * BK];   // 16 KB, linear, pitch 64 ushorts
    __shared__ unsigned short Bs[BN * BK];   // 16 KB
    __shared__ float sFB[64];

    const int tid = threadIdx.x;

    // bijective XCD swizzle: each XCD gets 512 consecutive logical blocks
    // (32 full bm-rows) -> Wt panels + A bands stay L2-resident per XCD.
    int id = blockIdx.x;
    int sw = (id & 7) * (GRID_WG / 8) + (id >> 3);
    const int bm = (sw >> 4) * BM;           // 256 M-blocks
    const int bn = (sw & 15) * BN;           // 16 N-blocks
    const int obase = bn >> 1;

    if (tid < 64) sFB[tid] = bias[NOUT + obase + tid];

    const int lane = tid & 63;
    const int wave = tid >> 6;
    const int wr = wave >> 1;          // 2x2 wave grid, 64x64 per wave
    const int wc = wave & 1;
    const int mrow = lane & 15;        // A row / B col within 16-tile
    const int q    = lane >> 4;        // 16B quarter within a 32-k half

    // ---- staging geometry: wave stages A rows 32w..+31 and B rows 32w..+31,
    // 4 issues each of 8 rows (64 lanes x 16B = 8 rows x 128B).
    //   lane l: row = 8i + (l>>3), phys quarter = l&7
    //   logical quarter = (l&7) ^ ((l>>3)&7)   [= p ^ (row&7), 8i%8==0]
    const int srow = lane >> 3;                      // 0..7 within an issue
    const int logq = (lane & 7) ^ (srow & 7);
    const int wrow = wave * 32;                      // wave's 32-row band
    const unsigned short* aSrc = Abf + (size_t)(bm + wrow + srow) * K_DIM + logq * 8;
    const unsigned short* bSrc = Wt  + (size_t)(bn + wrow + srow) * K_DIM + logq * 8;

    f32x4 acc[4][4];
    #pragma unroll
    for (int i = 0; i < 4; ++i)
        #pragma unroll
        for (int j = 0; j < 4; ++j)
            acc[i][j] = (f32x4){0.f, 0.f, 0.f, 0.f};

    const int sx = mrow & 7;           // read-side swizzle key (row&7)

    for (int k0 = 0; k0 < K_DIM; k0 += BK) {
        #pragma unroll
        for (int i = 0; i < 4; ++i) {
            gld_lds16(aSrc + (size_t)(8 * i) * K_DIM + k0, &As[(wrow + 8 * i) * BK]);
            gld_lds16(bSrc + (size_t)(8 * i) * K_DIM + k0, &Bs[(wrow + 8 * i) * BK]);
        }
        __syncthreads();   // drains vmcnt(0): tiles resident

        #pragma unroll
        for (int h = 0; h < 2; ++h) {
            const int pq = (h * 4 + q) ^ sx;   // phys 16B quarter
            bf16x8 a[4], b[4];
            #pragma unroll
            for (int mt = 0; mt < 4; ++mt)
                a[mt] = *(const bf16x8*)&As[(wr * 64 + mt * 16 + mrow) * BK + pq * 8];
            #pragma unroll
            for (int nt = 0; nt < 4; ++nt)
                b[nt] = *(const bf16x8*)&Bs[(wc * 64 + nt * 16 + mrow) * BK + pq * 8];
            #pragma unroll
            for (int mt = 0; mt < 4; ++mt)
                #pragma unroll
                for (int nt = 0; nt < 4; ++nt)
                    acc[mt][nt] = __builtin_amdgcn_mfma_f32_16x16x32_bf16(
                        a[mt], b[nt], acc[mt][nt], 0, 0, 0);
        }
        __syncthreads();   // all waves done reading before next-tile DMA
    }

    // ---- epilogue: pair even/odd columns via shfl_xor(1); lane parity == col parity
    const bool isOdd = (mrow & 1);
    #pragma unroll
    for (int mt = 0; mt < 4; ++mt) {
        #pragma unroll
        for (int nt = 0; nt < 4; ++nt) {
            int gcol = bn + wc * 64 + nt * 16 + mrow;
            int o = gcol >> 1;
            float fb = sFB[o - obase];
            #pragma unroll
            for (int r = 0; r < 4; ++r) {
                float x = acc[mt][nt][r];
                float p = __shfl_xor(x, 1, 64);            // partner column's value
                float uo = isOdd ? x : p;                  // the odd-gate pre-act
                float f = 1.f / (1.f + __expf(-(uo + fb)));
                int grow = bm + wr * 64 + mt * 16 + (lane >> 4) * 4 + r;
                size_t oi = (size_t)grow * NOUT + o;
                if (isOdd) fbuf[oi]  = f;
                else       u0buf[oi] = x * (1.f - f);
            }
        }
    }
}

// ---- fallback GEMM (fp32 A staged+converted in-kernel; only if ws too small)
#define LDAS 40
__global__ void gemm_f32_kernel(const float* __restrict__ A32,
                                const unsigned short* __restrict__ Wt,
                                const float* __restrict__ bias,
                                float* __restrict__ u0buf,
                                float* __restrict__ fbuf) {
    __shared__ unsigned short As[BM * LDAS];
    __shared__ unsigned short Bs[BN * LDAS];
    __shared__ float sFB[64];

    const int tid = threadIdx.x;
    const int bm = blockIdx.y * BM;
    const int bn = blockIdx.x * BN;
    const int obase = bn >> 1;

    if (tid < 64) sFB[tid] = bias[NOUT + obase + tid];

    const int lane = tid & 63;
    const int wave = tid >> 6;
    const int wr = wave >> 1;
    const int wc = wave & 1;
    const int mrow = lane & 15;
    const int kq = (lane >> 4) * 8;

    f32x4 acc[4][4];
    #pragma unroll
    for (int i = 0; i < 4; ++i)
        #pragma unroll
        for (int j = 0; j < 4; ++j)
            acc[i][j] = (f32x4){0.f, 0.f, 0.f, 0.f};

    for (int k0 = 0; k0 < K_DIM; k0 += 32) {
        #pragma unroll
        for (int r = 0; r < 4; ++r) {
            int idx = tid + r * 256;
            int row = idx >> 3;
            int kc  = (idx & 7) << 2;
            float4 v = *(const float4*)&A32[(size_t)(bm + row) * K_DIM + k0 + kc];
            us4 o = { f2bf(v.x), f2bf(v.y), f2bf(v.z), f2bf(v.w) };
            *(us4*)&As[row * LDAS + kc] = o;
        }
        #pragma unroll
        for (int r = 0; r < 2; ++r) {
            int idx = tid + r * 256;
            int row = idx >> 2;
            int kc  = (idx & 3) << 3;
            *(uint4*)&Bs[row * LDAS + kc] =
                *(const uint4*)&Wt[(size_t)(bn + row) * K_DIM + k0 + kc];
        }
        __syncthreads();

        bf16x8 a[4], b[4];
        #pragma unroll
        for (int mt = 0; mt < 4; ++mt)
            a[mt] = *(const bf16x8*)&As[(wr * 64 + mt * 16 + mrow) * LDAS + kq];
        #pragma unroll
        for (int nt = 0; nt < 4; ++nt)
            b[nt] = *(const bf16x8*)&Bs[(wc * 64 + nt * 16 + mrow) * LDAS + kq];
        #pragma unroll
        for (int mt = 0; mt < 4; ++mt)
            #pragma unroll
            for (int nt = 0; nt < 4; ++nt)
                acc[mt][nt] = __builtin_amdgcn_mfma_f32_16x16x32_bf16(
                    a[mt], b[nt], acc[mt][nt], 0, 0, 0);
        __syncthreads();
    }

    const bool isOdd = (mrow & 1);
    #pragma unroll
    for (int mt = 0; mt < 4; ++mt) {
        #pragma unroll
        for (int nt = 0; nt < 4; ++nt) {
            int gcol = bn + wc * 64 + nt * 16 + mrow;
            int o = gcol >> 1;
            float fb = sFB[o - obase];
            #pragma unroll
            for (int r = 0; r < 4; ++r) {
                float x = acc[mt][nt][r];
                float p = __shfl_xor(x, 1, 64);
                float uo = isOdd ? x : p;
                float f = 1.f / (1.f + __expf(-(uo + fb)));
                int grow = bm + wr * 64 + mt * 16 + (lane >> 4) * 4 + r;
                size_t oi = (size_t)grow * NOUT + o;
                if (isOdd) fbuf[oi]  = f;
                else       u0buf[oi] = x * (1.f - f);
            }
        }
    }
}

// ================= chunked scan (3 phases), float4-vectorized ===============
// Phase 1: per (4 cols, chunk c): compose chunk transform (F, U) with c_in = 0.
__global__ void scan_p1_kernel(const float* __restrict__ fgate,
                               const float* __restrict__ u0,     // cs buffer
                               float* __restrict__ Fbuf,
                               float* __restrict__ Ubuf) {
    int j4 = blockIdx.x * 256 + threadIdx.x;    // 0..NCOL/4-1
    int ch = blockIdx.y;                        // chunk 0..NCH-1
    size_t base = (size_t)ch * LC * NCOL + (size_t)j4 * 4;
    f32x4 F = {1.f, 1.f, 1.f, 1.f};
    f32x4 U = {0.f, 0.f, 0.f, 0.f};
    #pragma unroll 8
    for (int l = 0; l < LC; ++l) {
        size_t idx = base + (size_t)l * NCOL;
        f32x4 ft = *(const f32x4*)(fgate + idx);
        f32x4 ut = *(const f32x4*)(u0 + idx);
        #pragma unroll
        for (int c = 0; c < 4; ++c) {
            U[c] = fmaf(U[c], ft[c], ut[c]);
            F[c] = F[c] * ft[c];
        }
    }
    size_t ci = (size_t)ch * NCOL + (size_t)j4 * 4;
    *(f32x4*)(Fbuf + ci) = F;
    *(f32x4*)(Ubuf + ci) = U;
}

// Phase 2: per col, sequentially combine NCH chunk transforms -> carry-ins.
__global__ void scan_p2_kernel(const float* __restrict__ Fbuf,
                               const float* __restrict__ Ubuf,
                               const float* __restrict__ c_init,
                               float* __restrict__ carry,
                               float* __restrict__ c_final) {
    int j = blockIdx.x * 256 + threadIdx.x;
    float c = c_init[j];
    #pragma unroll
    for (int ch = 0; ch < NCH; ++ch) {
        size_t ci = (size_t)ch * NCOL + j;
        carry[ci] = c;
        c = fmaf(Fbuf[ci], c, Ubuf[ci]);
    }
    c_final[j] = c;
}

// Phase 3: per (4 cols, chunk): replay the exact FMA chain from carry-in.
__global__ void scan_p3_kernel(const float* __restrict__ fgate,
                               const float* __restrict__ carry,
                               float* __restrict__ cs) {          // holds u0
    int j4 = blockIdx.x * 256 + threadIdx.x;
    int ch = blockIdx.y;
    size_t base = (size_t)ch * LC * NCOL + (size_t)j4 * 4;
    f32x4 c = *(const f32x4*)(carry + (size_t)ch * NCOL + (size_t)j4 * 4);
    #pragma unroll 8
    for (int l = 0; l < LC; ++l) {
        size_t idx = base + (size_t)l * NCOL;
        f32x4 ft = *(const f32x4*)(fgate + idx);
        f32x4 ut = *(const f32x4*)(cs + idx);
        #pragma unroll
        for (int cc = 0; cc < 4; ++cc)
            c[cc] = fmaf(c[cc], ft[cc], ut[cc]);
        *(f32x4*)(cs + idx) = c;
    }
}

// Fallback single-pass scan (only if ws too small for chunk buffers)
__global__ void scan_kernel(const float* __restrict__ fgate,
                            const float* __restrict__ c_init,
                            float* __restrict__ cs,
                            float* __restrict__ c_final) {
    int j = blockIdx.x * 256 + threadIdx.x;
    float c = c_init[j];
    #pragma unroll 4
    for (int l = 0; l < L_DIM; ++l) {
        size_t idx = (size_t)l * NCOL + j;
        float ft = fgate[idx];
        float u  = cs[idx];
        c = fmaf(c, ft, u);
        cs[idx] = c;
    }
    c_final[j] = c;
}

extern "C" void kernel_launch(void* const* d_in, const int* in_sizes, int n_in,
                              void* d_out, int out_size, void* d_ws, size_t ws_size,
                              hipStream_t stream) {
    const float* input  = (const float*)d_in[0];  // [L,B,NIN]
    const float* c_init = (const float*)d_in[1];  // [B,NOUT]
    const float* weight = (const float*)d_in[2];  // [NIN, 2*NOUT]
    const float* bias   = (const float*)d_in[3];  // [2*NOUT]

    float* out_cs = (float*)d_out;                         // [L,B,NOUT]
    float* out_cf = out_cs + (size_t)L_DIM * B_DIM * NOUT; // [B,NOUT]
    float* out_fg = out_cf + (size_t)B_DIM * NOUT;         // [L,B,NOUT]

    // ws layout: [Wt bf16 4MB][Abf bf16 64MB][F 4MB][U 4MB][carry 4MB]
    size_t wt_bytes = (size_t)N_DIM * K_DIM * sizeof(unsigned short);
    size_t wt_pad   = (wt_bytes + 255) & ~(size_t)255;
    size_t a_bytes  = (size_t)M_DIM * K_DIM * sizeof(unsigned short);
    size_t ch_bytes = (size_t)NCH * NCOL * sizeof(float);  // 4 MB each
    unsigned short* Wt  = (unsigned short*)d_ws;
    unsigned short* Abf = (unsigned short*)((char*)d_ws + wt_pad);
    bool pre_a = (ws_size >= wt_pad + a_bytes);
    size_t scan_off = pre_a ? (wt_pad + a_bytes) : wt_pad;
    float* Fbuf  = (float*)((char*)d_ws + scan_off);
    float* Ubuf  = Fbuf + NCH * NCOL;
    float* carry = Ubuf + NCH * NCOL;
    bool chunked = (ws_size >= scan_off + 3 * ch_bytes);

    // 1) weight fp32 [K][N] -> bf16 Wt [N][K]
    cvt_weight_kernel<<<dim3(N_DIM / 32, K_DIM / 32), dim3(32, 8), 0, stream>>>(weight, Wt);

    // 2) input fp32 -> bf16 (skippable fallback if ws too small)
    if (pre_a) {
        int nblk = (M_DIM * K_DIM) / (8 * 256);  // 16384
        cvt_input_kernel<<<nblk, 256, 0, stream>>>(input, Abf);
    }

    // 3) GEMM + gate epilogue: u0 -> out_cs (temp), forget -> out_fg
    if (pre_a) {
        gemm_lds_kernel<<<GRID_WG, 256, 0, stream>>>(Abf, Wt, bias, out_cs, out_fg);
    } else {
        dim3 ggrid(N_DIM / BN, M_DIM / BM);      // (16, 256)
        gemm_f32_kernel<<<ggrid, 256, 0, stream>>>(input, Wt, bias, out_cs, out_fg);
    }

    // 4) recurrence: chunked 3-phase scan (falls back to single-pass if no ws)
    if (chunked) {
        dim3 sgrid(NCOL / 1024, NCH);            // (16, 64), float4 per thread
        scan_p1_kernel<<<sgrid, 256, 0, stream>>>(out_fg, out_cs, Fbuf, Ubuf);
        scan_p2_kernel<<<NCOL / 256, 256, 0, stream>>>(Fbuf, Ubuf, c_init, carry, out_cf);
        scan_p3_kernel<<<sgrid, 256, 0, stream>>>(out_fg, carry, out_cs);
    } else {
        scan_kernel<<<NCOL / 256, 256, 0, stream>>>(out_fg, c_init, out_cs, out_cf);
    }
}